// Round 5
// baseline (193.228 us; speedup 1.0000x reference)
//
#include <hip/hip_runtime.h>

// Problem constants (fixed by the reference setup_inputs)
#define N_PTS 8192   // points per batch
#define M_Q   2048   // query points per batch
#define C_F   64     // feature channels
#define NS    32     // nsample
#define B_SZ  8      // batch

// native clang vector — __builtin_nontemporal_store requires this (HIP's
// float4 is a class and is rejected by the builtin).
typedef float f32x4 __attribute__((ext_vector_type(4)));

// ---------------------------------------------------------------------------
// K1: prep (vectorized).
//  blocks [0, 1024):   transpose feat (b,c,n) -> featT (b,n,c). 64x64 tile.
//    float4 global loads along n, float4 global stores along c; LDS row
//    stride 65 floats keeps both scalar sides <=2-way on banks (free, m136).
//  blocks [1024, 1280): xyz4[b*N+n] = (x, y, z, p2sum). p2sum in the exact
//    numpy f32 order ((x*x+y*y)+z*z), contract OFF — feeds the pinned d2
//    formula bit-for-bit (unchanged from the verified kernel).
// ---------------------------------------------------------------------------
__global__ __launch_bounds__(256) void prep_kernel(
    const float* __restrict__ feat, const float* __restrict__ xyz,
    float* __restrict__ featT, float4* __restrict__ xyz4)
{
#pragma clang fp contract(off)
    __shared__ float lds[C_F * 65];
    if (blockIdx.x < B_SZ * 128) {
        const int b  = blockIdx.x >> 7;        // 128 n-tiles per batch
        const int n0 = (blockIdx.x & 127) * 64;
        {
            const int c_lo = (int)threadIdx.x >> 4;        // 0..15
            const int n4   = ((int)threadIdx.x & 15) * 4;  // 0..60
#pragma unroll
            for (int k = 0; k < 4; ++k) {
                const int c = k * 16 + c_lo;
                const float4 v =
                    *(const float4*)&feat[((size_t)b * C_F + c) * N_PTS + n0 + n4];
                lds[c * 65 + n4 + 0] = v.x;
                lds[c * 65 + n4 + 1] = v.y;
                lds[c * 65 + n4 + 2] = v.z;
                lds[c * 65 + n4 + 3] = v.w;
            }
        }
        __syncthreads();
        {
            const int n_lo = (int)threadIdx.x >> 4;        // 0..15
            const int c0   = ((int)threadIdx.x & 15) * 4;  // 0..60
#pragma unroll
            for (int k = 0; k < 4; ++k) {
                const int nn = k * 16 + n_lo;
                float4 w;
                w.x = lds[(c0 + 0) * 65 + nn];
                w.y = lds[(c0 + 1) * 65 + nn];
                w.z = lds[(c0 + 2) * 65 + nn];
                w.w = lds[(c0 + 3) * 65 + nn];
                *(float4*)&featT[((size_t)b * N_PTS + n0 + nn) * C_F + c0] = w;
            }
        }
    } else {
        const int i = (blockIdx.x - B_SZ * 128) * 256 + (int)threadIdx.x; // 0..B*N-1
        const float p0 = xyz[i * 3 + 0];
        const float p1 = xyz[i * 3 + 1];
        const float p2 = xyz[i * 3 + 2];
        const float s  = (p0 * p0 + p1 * p1) + p2 * p2;   // np.sum order, no fma
        xyz4[i] = make_float4(p0, p1, p2, s);
    }
}

// ---------------------------------------------------------------------------
// K2: fused ball-query + gather. Block = 256 threads = 4 waves = 4 queries.
//
// Scan (per wave): macro-chunks of 256 pts, double-buffered loads.
// NUMERICS (pinned, verified absmax=0 across 3 sessions): d2 = (q2 + p2sum)
// - 2*qp, all partials left-to-right f32, contract OFF.
//
// Gather: PER-WAVE PARALLEL — wave w gathers its own query's 32 feature
// rows into its private 32-column slice of a 4-query-wide stage
// (67 rows x 132 cols, stride 132 -> b128 reads conflict-free, scalar
// writes ~4-way). sidx is wave-private (written+read by the same wave), so
// the scan->gather barrier disappears; ONE barrier per block total (vs 8).
//
// Store: the block's 4 queries are consecutive m, so each output row is a
// single 512 B contiguous burst (4x fewer scatter points than per-query
// rounds). Nontemporal: out is never re-read; keeps featT resident in L2.
// ---------------------------------------------------------------------------
__global__ __launch_bounds__(256) void qbg_kernel(
    const float4* __restrict__ xyz4, const float* __restrict__ nxyz,
    const float* __restrict__ featT, float* __restrict__ out)
{
#pragma clang fp contract(off)
    __shared__ int   sidx[4][NS];
    __shared__ float stage[67 * 132];             // 35.4 KB, 4 queries wide

    const int lane = threadIdx.x & 63;
    const int w    = threadIdx.x >> 6;            // wave id 0..3
    const int q    = blockIdx.x * 4 + w;          // this wave's query
    const int b    = q >> 11;                     // M_Q = 2048
    const float4* __restrict__ xb = xyz4 + (size_t)b * N_PTS;

    const float* __restrict__ qp = nxyz + (size_t)q * 3;
    const float qx = qp[0], qy = qp[1], qz = qp[2];

    {
        const float q2 = (qx * qx + qy * qy) + qz * qz;   // np.sum order

        int  cnt = 0;
        int  first_idx = 0;
        bool have_first = false;

        float4 P[4], Q[4];
#pragma unroll
        for (int cc = 0; cc < 4; ++cc) P[cc] = xb[cc * 64 + lane];

        for (int base = 0; base < N_PTS && cnt < NS; base += 256) {
            const int nb = base + 256;
            if (nb < N_PTS) {
#pragma unroll
                for (int cc = 0; cc < 4; ++cc) Q[cc] = xb[nb + cc * 64 + lane];
            }
#pragma unroll
            for (int cc = 0; cc < 4; ++cc) {
                if (cnt >= NS) break;                       // wave-uniform
                const float qpdot = (qx * P[cc].x + qy * P[cc].y) + qz * P[cc].z;
                const float d2 = (q2 + P[cc].w) - 2.0f * qpdot;   // ref formula
                const bool pred = d2 < 1.0f;
                const unsigned long long mask = __ballot(pred);
                if (mask) {
                    if (!have_first) {
                        first_idx = base + cc * 64 + __ffsll(mask) - 1;
                        have_first = true;
                    }
                    if (pred) {
                        const int pos = cnt + (int)__popcll(mask & ((1ull << lane) - 1ull));
                        if (pos < NS) sidx[w][pos] = base + cc * 64 + lane;
                    }
                    cnt += (int)__popcll(mask);
                }
            }
#pragma unroll
            for (int cc = 0; cc < 4; ++cc) P[cc] = Q[cc];
        }
        if (cnt < NS) {
            for (int p = cnt + lane; p < NS; p += 64) sidx[w][p] = first_idx;
        }
    }
    // NO barrier: sidx[w] is wave-private; stage slices are disjoint per wave.

    // ---- gather: wave w fills stage[:, w*32 .. w*32+31] ----
    {
        const int sj = lane & 7;                  // lane-within-sample
        const int sa = lane >> 3;                 // sample sub-id 0..7
#pragma unroll
        for (int it = 0; it < 4; ++it) {
            const int s  = it * 8 + sa;           // sample 0..31
            const int n  = sidx[w][s];
            const int col = w * NS + s;
            const float* __restrict__ fb = featT + ((size_t)b * N_PTS + n) * C_F;
            const float4 va = *(const float4*)(fb + sj * 4);
            const float4 vb = *(const float4*)(fb + 32 + sj * 4);
            const int ca = sj * 4;
            stage[(3 + ca + 0)  * 132 + col] = va.x;
            stage[(3 + ca + 1)  * 132 + col] = va.y;
            stage[(3 + ca + 2)  * 132 + col] = va.z;
            stage[(3 + ca + 3)  * 132 + col] = va.w;
            stage[(35 + ca + 0) * 132 + col] = vb.x;
            stage[(35 + ca + 1) * 132 + col] = vb.y;
            stage[(35 + ca + 2) * 132 + col] = vb.z;
            stage[(35 + ca + 3) * 132 + col] = vb.w;
            if (sj == 0) {
                const float4 pv = xb[n];
                stage[0 * 132 + col] = pv.x - qx;   // exact ref subtract
                stage[1 * 132 + col] = pv.y - qy;
                stage[2 * 132 + col] = pv.z - qz;
            }
        }
    }
    __syncthreads();   // the block's ONLY barrier

    // ---- store: 67 rows x 32 float4 = 2144 bursts, 512 B contiguous/row ----
    const int mm0 = (blockIdx.x * 4) & (M_Q - 1);
    const size_t cstride = (size_t)M_Q * NS;      // 65536 floats per channel
    float* __restrict__ op = out + ((size_t)b * 67 * M_Q + mm0) * NS;
#pragma unroll
    for (int it = 0; it < 9; ++it) {
        const int e = it * 256 + (int)threadIdx.x;
        if (e < 67 * 32) {
            const int row = e >> 5;               // 0..66
            const int c4  = e & 31;               // 16B chunk within 512B row
            const f32x4 v = *(const f32x4*)&stage[row * 132 + c4 * 4];
            __builtin_nontemporal_store(
                v, (f32x4*)&op[(size_t)row * cstride + c4 * 4]);
        }
    }
}

extern "C" void kernel_launch(void* const* d_in, const int* in_sizes, int n_in,
                              void* d_out, int out_size, void* d_ws, size_t ws_size,
                              hipStream_t stream)
{
    const float* xyz  = (const float*)d_in[0];   // (B, N, 3)
    const float* nxyz = (const float*)d_in[1];   // (B, M, 3)
    const float* feat = (const float*)d_in[2];   // (B, C, N)
    float* out = (float*)d_out;                  // (B, 67, M, 32)

    float*  featT = (float*)d_ws;                             // 16.8 MB
    float4* xyz4  = (float4*)((char*)d_ws + (20 << 20));      // 1 MB

    const int Q = B_SZ * M_Q;                    // 16384 queries

    prep_kernel<<<B_SZ * 128 + (B_SZ * N_PTS) / 256, 256, 0, stream>>>(
        feat, xyz, featT, xyz4);
    qbg_kernel<<<Q / 4, 256, 0, stream>>>(xyz4, nxyz, featT, out);
}

// Round 6
// 184.340 us; speedup vs baseline: 1.0482x; 1.0482x over previous
//
#include <hip/hip_runtime.h>

// Problem constants (fixed by the reference setup_inputs)
#define N_PTS 8192   // points per batch
#define M_Q   2048   // query points per batch
#define C_F   64     // feature channels
#define NS    32     // nsample
#define B_SZ  8      // batch

// native clang vector — __builtin_nontemporal_store requires this (HIP's
// float4 is a class and is rejected by the builtin).
typedef float f32x4 __attribute__((ext_vector_type(4)));

// ---------------------------------------------------------------------------
// K1: prep (vectorized, XCD batch-affinity).
//  blocks [0, 1024):   transpose feat (b,c,n) -> featT (b,n,c). 64x64 tile.
//    SWIZZLE: b = blockIdx & 7 — all tiles of batch b run on XCD b (dispatch
//    round-robins blockIdx%8), so featT[b] (2 MB) is written THROUGH XCD b's
//    4 MB L2, pre-warming it for qbg's reads of the same batch.
//  blocks [1024, 1280): xyz4[b*N+n] = (x, y, z, p2sum), same affinity.
//    p2sum in the exact numpy f32 order ((x*x+y*y)+z*z), contract OFF —
//    feeds the pinned d2 formula bit-for-bit (unchanged, verified absmax=0).
// ---------------------------------------------------------------------------
__global__ __launch_bounds__(256) void prep_kernel(
    const float* __restrict__ feat, const float* __restrict__ xyz,
    float* __restrict__ featT, float4* __restrict__ xyz4)
{
#pragma clang fp contract(off)
    __shared__ float lds[C_F * 65];
    if (blockIdx.x < B_SZ * 128) {
        const int b  = (int)blockIdx.x & 7;            // batch = XCD
        const int n0 = ((int)blockIdx.x >> 3) * 64;    // n-tile 0..127
        {
            const int c_lo = (int)threadIdx.x >> 4;        // 0..15
            const int n4   = ((int)threadIdx.x & 15) * 4;  // 0..60
#pragma unroll
            for (int k = 0; k < 4; ++k) {
                const int c = k * 16 + c_lo;
                const float4 v =
                    *(const float4*)&feat[((size_t)b * C_F + c) * N_PTS + n0 + n4];
                lds[c * 65 + n4 + 0] = v.x;
                lds[c * 65 + n4 + 1] = v.y;
                lds[c * 65 + n4 + 2] = v.z;
                lds[c * 65 + n4 + 3] = v.w;
            }
        }
        __syncthreads();
        {
            const int n_lo = (int)threadIdx.x >> 4;        // 0..15
            const int c0   = ((int)threadIdx.x & 15) * 4;  // 0..60
#pragma unroll
            for (int k = 0; k < 4; ++k) {
                const int nn = k * 16 + n_lo;
                float4 w;
                w.x = lds[(c0 + 0) * 65 + nn];
                w.y = lds[(c0 + 1) * 65 + nn];
                w.z = lds[(c0 + 2) * 65 + nn];
                w.w = lds[(c0 + 3) * 65 + nn];
                *(float4*)&featT[((size_t)b * N_PTS + n0 + nn) * C_F + c0] = w;
            }
        }
    } else {
        const int j  = (int)blockIdx.x - B_SZ * 128;   // 0..255
        const int b  = j & 7;                          // batch = XCD
        const int ch = j >> 3;                         // 0..31 chunk
        const int i  = b * N_PTS + ch * 256 + (int)threadIdx.x;
        const float p0 = xyz[i * 3 + 0];
        const float p1 = xyz[i * 3 + 1];
        const float p2 = xyz[i * 3 + 2];
        const float s  = (p0 * p0 + p1 * p1) + p2 * p2;   // np.sum order, no fma
        xyz4[i] = make_float4(p0, p1, p2, s);
    }
}

// ---------------------------------------------------------------------------
// K2: fused ball-query + gather. Block = 256 threads = 4 waves = 4 queries.
//
// XCD batch-affinity swizzle: b = blockIdx & 7, slice = blockIdx >> 3 —
// all 512 blocks of batch b run on XCD b, whose L2 holds that batch's
// entire featT (2 MB) + xyz4 (128 KB), pre-warmed by prep. The gather's
// ~134 MB of featT row-reads become L2 hits instead of L3/HBM traffic.
//
// Scan (per wave): macro-chunks of 256 pts, double-buffered loads.
// NUMERICS (pinned, verified absmax=0): d2 = (q2 + p2sum) - 2*qp, all
// partials left-to-right f32, contract OFF — byte-identical to r0's code.
//
// Gather (whole block, per query): T14 async-stage split — round w2+1's
// featT row loads are issued into registers BEFORE round w2's barrier +
// 536-store stream. Stores nontemporal: out is never re-read, and keeping
// the 17.6 MB/XCD store stream out of L2 protects featT residency.
// ---------------------------------------------------------------------------
__global__ __launch_bounds__(256) void qbg_kernel(
    const float4* __restrict__ xyz4, const float* __restrict__ nxyz,
    const float* __restrict__ featT, float* __restrict__ out)
{
#pragma clang fp contract(off)
    __shared__ int   sidx[4][NS];
    __shared__ float stage[67 * 33];

    const int lane = threadIdx.x & 63;
    const int w    = threadIdx.x >> 6;            // wave id 0..3
    const int b    = (int)blockIdx.x & 7;         // batch = XCD
    const int s4   = (int)blockIdx.x >> 3;        // slice 0..511 within batch
    const int q0   = (b << 11) + s4 * 4;          // block's first query
    const int q    = q0 + w;                      // this wave's query
    const float4* __restrict__ xb = xyz4 + (size_t)b * N_PTS;

    {
        const float* __restrict__ qp = nxyz + (size_t)q * 3;
        const float qx = qp[0], qy = qp[1], qz = qp[2];
        const float q2 = (qx * qx + qy * qy) + qz * qz;   // np.sum order

        int  cnt = 0;
        int  first_idx = 0;
        bool have_first = false;

        float4 P[4], Q[4];
#pragma unroll
        for (int cc = 0; cc < 4; ++cc) P[cc] = xb[cc * 64 + lane];

        for (int base = 0; base < N_PTS && cnt < NS; base += 256) {
            const int nb = base + 256;
            if (nb < N_PTS) {
#pragma unroll
                for (int cc = 0; cc < 4; ++cc) Q[cc] = xb[nb + cc * 64 + lane];
            }
#pragma unroll
            for (int cc = 0; cc < 4; ++cc) {
                if (cnt >= NS) break;                       // wave-uniform
                const float qpdot = (qx * P[cc].x + qy * P[cc].y) + qz * P[cc].z;
                const float d2 = (q2 + P[cc].w) - 2.0f * qpdot;   // ref formula
                const bool pred = d2 < 1.0f;
                const unsigned long long mask = __ballot(pred);
                if (mask) {
                    if (!have_first) {
                        first_idx = base + cc * 64 + __ffsll(mask) - 1;
                        have_first = true;
                    }
                    if (pred) {
                        const int pos = cnt + (int)__popcll(mask & ((1ull << lane) - 1ull));
                        if (pos < NS) sidx[w][pos] = base + cc * 64 + lane;
                    }
                    cnt += (int)__popcll(mask);
                }
            }
#pragma unroll
            for (int cc = 0; cc < 4; ++cc) P[cc] = Q[cc];
        }
        if (cnt < NS) {
            for (int p = cnt + lane; p < NS; p += 64) sidx[w][p] = first_idx;
        }
    }
    __syncthreads();

    // ---- gather phase: 4 queries, sequentially, whole block each ----
    const int pS = threadIdx.x >> 3;              // sample 0..31
    const int j  = threadIdx.x & 7;               // lane-within-sample
    const size_t cstride = (size_t)M_Q * NS;      // 65536

    // prefetch round 0
    float4 va, vb, pv;
    float q0v = 0.f, q1v = 0.f, q2v = 0.f;
    {
        const int n0 = sidx[0][pS];
        const float* __restrict__ fb = featT + ((size_t)b * N_PTS + n0) * C_F;
        va = *(const float4*)(fb + j * 4);
        vb = *(const float4*)(fb + 32 + j * 4);
        if (j == 0) {
            pv = xb[n0];
            const float* __restrict__ qp2 = nxyz + (size_t)q0 * 3;
            q0v = qp2[0]; q1v = qp2[1]; q2v = qp2[2];
        }
    }

    for (int w2 = 0; w2 < 4; ++w2) {
        // stage current round's prefetched registers
        const int ca = j * 4;
        stage[(3 + ca + 0)  * 33 + pS] = va.x;
        stage[(3 + ca + 1)  * 33 + pS] = va.y;
        stage[(3 + ca + 2)  * 33 + pS] = va.z;
        stage[(3 + ca + 3)  * 33 + pS] = va.w;
        stage[(35 + ca + 0) * 33 + pS] = vb.x;
        stage[(35 + ca + 1) * 33 + pS] = vb.y;
        stage[(35 + ca + 2) * 33 + pS] = vb.z;
        stage[(35 + ca + 3) * 33 + pS] = vb.w;
        if (j == 0) {
            stage[0 * 33 + pS] = pv.x - q0v;
            stage[1 * 33 + pS] = pv.y - q1v;
            stage[2 * 33 + pS] = pv.z - q2v;
        }

        // issue next round's loads (overlap barrier + store stream)
        float4 van, vbn, pvn;
        float q0n = 0.f, q1n = 0.f, q2n = 0.f;
        if (w2 < 3) {
            const int nx = sidx[w2 + 1][pS];
            const float* __restrict__ fb = featT + ((size_t)b * N_PTS + nx) * C_F;
            van = *(const float4*)(fb + j * 4);
            vbn = *(const float4*)(fb + 32 + j * 4);
            if (j == 0) {
                pvn = xb[nx];
                const float* __restrict__ qp2 =
                    nxyz + (size_t)(q0 + w2 + 1) * 3;
                q0n = qp2[0]; q1n = qp2[1]; q2n = qp2[2];
            }
        }
        __syncthreads();

        // 67 rows x 8 float4 = 536 nontemporal vector stores
        const int qq = q0 + w2;
        const int mm = qq & (M_Q - 1);
        const size_t obase = ((size_t)b * 67 * M_Q + mm) * NS;
#pragma unroll
        for (int it = 0; it < 3; ++it) {
            const int e = it * 256 + (int)threadIdx.x;
            if (e < 67 * 8) {
                const int row  = e >> 3;
                const int col4 = (e & 7) * 4;
                f32x4 v;
                v.x = stage[row * 33 + col4 + 0];
                v.y = stage[row * 33 + col4 + 1];
                v.z = stage[row * 33 + col4 + 2];
                v.w = stage[row * 33 + col4 + 3];
                __builtin_nontemporal_store(
                    v, (f32x4*)&out[obase + (size_t)row * cstride + col4]);
            }
        }
        __syncthreads();   // stage reused next round

        va = van; vb = vbn; pv = pvn;
        q0v = q0n; q1v = q1n; q2v = q2n;
    }
}

extern "C" void kernel_launch(void* const* d_in, const int* in_sizes, int n_in,
                              void* d_out, int out_size, void* d_ws, size_t ws_size,
                              hipStream_t stream)
{
    const float* xyz  = (const float*)d_in[0];   // (B, N, 3)
    const float* nxyz = (const float*)d_in[1];   // (B, M, 3)
    const float* feat = (const float*)d_in[2];   // (B, C, N)
    float* out = (float*)d_out;                  // (B, 67, M, 32)

    float*  featT = (float*)d_ws;                             // 16.8 MB
    float4* xyz4  = (float4*)((char*)d_ws + (20 << 20));      // 1 MB

    const int Q = B_SZ * M_Q;                    // 16384 queries

    prep_kernel<<<B_SZ * 128 + (B_SZ * N_PTS) / 256, 256, 0, stream>>>(
        feat, xyz, featT, xyz4);
    qbg_kernel<<<Q / 4, 256, 0, stream>>>(xyz4, nxyz, featT, out);
}

// Round 7
// 177.926 us; speedup vs baseline: 1.0860x; 1.0360x over previous
//
#include <hip/hip_runtime.h>

// Problem constants (fixed by the reference setup_inputs)
#define N_PTS 8192   // points per batch
#define M_Q   2048   // query points per batch
#define C_F   64     // feature channels
#define NS    32     // nsample
#define B_SZ  8      // batch

// ---------------------------------------------------------------------------
// K1: prep.
//  blocks [0, 1024):   transpose feat (b,c,n) -> featT (b,n,c). 64x64 LDS
//                      tile, stride 65 (2-way bank = free).
//  blocks [1024, 1280): xyz4[b*N+n] = (x, y, z, p2sum). p2sum computed in the
//                      exact numpy f32 order ((x*x+y*y)+z*z), contract OFF —
//                      this value feeds the pinned d2 formula bit-for-bit.
// ---------------------------------------------------------------------------
__global__ __launch_bounds__(256) void prep_kernel(
    const float* __restrict__ feat, const float* __restrict__ xyz,
    float* __restrict__ featT, float4* __restrict__ xyz4)
{
#pragma clang fp contract(off)
    __shared__ float lds[C_F * 65];
    if (blockIdx.x < B_SZ * 128) {
        const int b  = blockIdx.x >> 7;        // 128 n-tiles per batch
        const int n0 = (blockIdx.x & 127) * 64;
        {
            const int c4 = threadIdx.x >> 6;   // 0..3
            const int nn = threadIdx.x & 63;
#pragma unroll
            for (int k = 0; k < 16; ++k) {
                const int c = k * 4 + c4;
                lds[c * 65 + nn] = feat[((size_t)b * C_F + c) * N_PTS + n0 + nn];
            }
        }
        __syncthreads();
        {
            const int n4 = threadIdx.x >> 6;   // 0..3
            const int c  = threadIdx.x & 63;
#pragma unroll
            for (int k = 0; k < 16; ++k) {
                const int nn = k * 4 + n4;
                featT[((size_t)b * N_PTS + n0 + nn) * C_F + c] = lds[c * 65 + nn];
            }
        }
    } else {
        const int i = (blockIdx.x - B_SZ * 128) * 256 + (int)threadIdx.x; // 0..B*N-1
        const float p0 = xyz[i * 3 + 0];
        const float p1 = xyz[i * 3 + 1];
        const float p2 = xyz[i * 3 + 2];
        const float s  = (p0 * p0 + p1 * p1) + p2 * p2;   // np.sum order, no fma
        xyz4[i] = make_float4(p0, p1, p2, s);
    }
}

// ---------------------------------------------------------------------------
// K2: fused ball-query + gather. Block = 256 threads = 4 waves = 4 queries.
//
// Scan phase (per wave): macro-chunks of 256 points, 4 dwordx4 loads issued
// up front, then 4 ballot/compact rounds; early-exit at 32 hits (wave-uniform
// cnt). Hit indices land in LDS sidx[w][*] — no global idx round-trip.
// NUMERICS (pinned, rounds 2-3 passed absmax=0): d2 = (q2 + p2sum) - 2*qp,
// all partials left-to-right f32, contract OFF, bit-matching numpy.
//
// Gather phase (whole block, per query sequentially): 8 lanes/sample read
// featT[b,n,:] as 2 float4s (fully-used 64B lines), stage into LDS stride 33
// (~2-way bank = free), then 536 float4 global stores (obase 128B-aligned).
// Co-schedule win: heavy-tail scan blocks (full 8192-pt scan) hide under
// other blocks' BW-bound output stores.
// ---------------------------------------------------------------------------
__global__ __launch_bounds__(256) void qbg_kernel(
    const float4* __restrict__ xyz4, const float* __restrict__ nxyz,
    const float* __restrict__ featT, float* __restrict__ out)
{
#pragma clang fp contract(off)
    __shared__ int   sidx[4][NS];
    __shared__ float stage[67 * 33];

    const int lane = threadIdx.x & 63;
    const int w    = threadIdx.x >> 6;            // wave id 0..3
    const int q    = blockIdx.x * 4 + w;          // this wave's query
    const int b    = q >> 11;                     // M_Q = 2048
    const float4* __restrict__ xb = xyz4 + (size_t)b * N_PTS;

    {
        const float* __restrict__ qp = nxyz + (size_t)q * 3;
        const float qx = qp[0], qy = qp[1], qz = qp[2];
        const float q2 = (qx * qx + qy * qy) + qz * qz;   // np.sum order

        int  cnt = 0;
        int  first_idx = 0;
        bool have_first = false;

        for (int base = 0; base < N_PTS && cnt < NS; base += 256) {
            float4 P[4];
#pragma unroll
            for (int cc = 0; cc < 4; ++cc)
                P[cc] = xb[base + cc * 64 + lane];
#pragma unroll
            for (int cc = 0; cc < 4; ++cc) {
                if (cnt >= NS) break;                       // wave-uniform
                const float qpdot = (qx * P[cc].x + qy * P[cc].y) + qz * P[cc].z;
                const float d2 = (q2 + P[cc].w) - 2.0f * qpdot;   // ref formula
                const bool pred = d2 < 1.0f;
                const unsigned long long mask = __ballot(pred);
                if (mask) {
                    if (!have_first) {
                        first_idx = base + cc * 64 + __ffsll(mask) - 1;
                        have_first = true;
                    }
                    if (pred) {
                        const int pos = cnt + (int)__popcll(mask & ((1ull << lane) - 1ull));
                        if (pos < NS) sidx[w][pos] = base + cc * 64 + lane;
                    }
                    cnt += (int)__popcll(mask);
                }
            }
        }
        if (cnt < NS) {
            for (int p = cnt + lane; p < NS; p += 64) sidx[w][p] = first_idx;
        }
    }
    __syncthreads();

    // ---- gather phase: 4 queries, sequentially, whole block each ----
    const int pS = threadIdx.x >> 3;              // sample 0..31
    const int j  = threadIdx.x & 7;               // lane-within-sample
    const size_t cstride = (size_t)M_Q * NS;      // 65536

    for (int w2 = 0; w2 < 4; ++w2) {
        const int qq = blockIdx.x * 4 + w2;
        const int mm = qq & (M_Q - 1);
        const int n  = sidx[w2][pS];

        const float* __restrict__ fb = featT + ((size_t)b * N_PTS + n) * C_F;
#pragma unroll
        for (int k = 0; k < 2; ++k) {
            const int c = k * 32 + j * 4;                    // 16B-aligned
            const float4 v = *(const float4*)(fb + c);
            stage[(3 + c + 0) * 33 + pS] = v.x;
            stage[(3 + c + 1) * 33 + pS] = v.y;
            stage[(3 + c + 2) * 33 + pS] = v.z;
            stage[(3 + c + 3) * 33 + pS] = v.w;
        }
        if (j == 0) {
            const float4 pv = xb[n];
            const float* __restrict__ qp2 = nxyz + (size_t)qq * 3;
            stage[0 * 33 + pS] = pv.x - qp2[0];
            stage[1 * 33 + pS] = pv.y - qp2[1];
            stage[2 * 33 + pS] = pv.z - qp2[2];
        }
        __syncthreads();

        // 67 rows x 8 float4 = 536 vector stores; LDS reads scalar (stride 33
        // keeps them ~2-way = free), global stores dwordx4 (16B-aligned).
        const size_t obase = ((size_t)b * 67 * M_Q + mm) * NS;
#pragma unroll
        for (int it = 0; it < 3; ++it) {
            const int e = it * 256 + (int)threadIdx.x;
            if (e < 67 * 8) {
                const int row  = e >> 3;
                const int col4 = (e & 7) * 4;
                float4 v;
                v.x = stage[row * 33 + col4 + 0];
                v.y = stage[row * 33 + col4 + 1];
                v.z = stage[row * 33 + col4 + 2];
                v.w = stage[row * 33 + col4 + 3];
                *(float4*)&out[obase + (size_t)row * cstride + col4] = v;
            }
        }
        __syncthreads();   // stage reused next w2
    }
}

extern "C" void kernel_launch(void* const* d_in, const int* in_sizes, int n_in,
                              void* d_out, int out_size, void* d_ws, size_t ws_size,
                              hipStream_t stream)
{
    const float* xyz  = (const float*)d_in[0];   // (B, N, 3)
    const float* nxyz = (const float*)d_in[1];   // (B, M, 3)
    const float* feat = (const float*)d_in[2];   // (B, C, N)
    float* out = (float*)d_out;                  // (B, 67, M, 32)

    float*  featT = (float*)d_ws;                             // 16.8 MB
    float4* xyz4  = (float4*)((char*)d_ws + (20 << 20));      // 1 MB

    const int Q = B_SZ * M_Q;                    // 16384 queries

    prep_kernel<<<B_SZ * 128 + (B_SZ * N_PTS) / 256, 256, 0, stream>>>(
        feat, xyz, featT, xyz4);
    qbg_kernel<<<Q / 4, 256, 0, stream>>>(xyz4, nxyz, featT, out);
}